// Round 1
// baseline (8809.834 us; speedup 1.0000x reference)
//
#include <hip/hip_runtime.h>

#define BATCH 16
#define NP1 4096
#define NP2 2048
#define NP3 1024

// IEEE ops that the compiler may NOT contract/reorder — used for every distance
// that feeds a discrete decision (kNN membership, FPS argmax). Order matches the
// reference: norms (x*x+y*y)+z*z ; knn d = (ni+nj) - 2*dot ; fps d = (dx^2+dy^2)+dz^2.
__device__ __forceinline__ float f_add(float a, float b) { return __fadd_rn(a, b); }
__device__ __forceinline__ float f_mul(float a, float b) { return __fmul_rn(a, b); }
__device__ __forceinline__ float f_sub(float a, float b) { return __fsub_rn(a, b); }
__device__ __forceinline__ float sqnorm3(float x, float y, float z) {
  return f_add(f_add(f_mul(x, x), f_mul(y, y)), f_mul(z, z));
}

// ---------------- kNN: for each query (optionally an FPS-sampled subset),
// K smallest squared distances over all NC candidates, tie -> lower index.
template<int K, int NC>
__global__ __launch_bounds__(256) void knn_kernel(
    const float* __restrict__ pos, const int* __restrict__ qidx, int NQ,
    int* __restrict__ out_idx)
{
  const int b = blockIdx.y;
  const int s = blockIdx.x * 256 + threadIdx.x;
  const int i = qidx ? qidx[b * NQ + s] : s;
  const float* P = pos + (size_t)b * NC * 3;
  const float xi = P[i * 3 + 0], yi = P[i * 3 + 1], zi = P[i * 3 + 2];
  const float ni = sqnorm3(xi, yi, zi);
  float bd[K]; int bj[K];
#pragma unroll
  for (int t = 0; t < K; ++t) { bd[t] = __builtin_inff(); bj[t] = 0; }
  __shared__ float4 tile[1024];
  for (int base = 0; base < NC; base += 1024) {
    __syncthreads();
    for (int t = threadIdx.x; t < 1024; t += 256) {
      const float* q = P + (size_t)(base + t) * 3;
      const float x = q[0], y = q[1], z = q[2];
      tile[t] = make_float4(x, y, z, sqnorm3(x, y, z));
    }
    __syncthreads();
#pragma unroll 2
    for (int t = 0; t < 1024; ++t) {
      const float4 q = tile[t];
      const float dot = f_add(f_add(f_mul(xi, q.x), f_mul(yi, q.y)), f_mul(zi, q.z));
      const float d = f_sub(f_add(ni, q.w), f_mul(2.0f, dot));
      if (d < bd[K - 1]) {          // strict < keeps earlier index on ties
        bd[K - 1] = d; bj[K - 1] = base + t;
#pragma unroll
        for (int r = K - 1; r > 0; --r) {
          if (bd[r] < bd[r - 1]) {  // strict < : equal values keep insertion (index) order
            float td = bd[r]; bd[r] = bd[r - 1]; bd[r - 1] = td;
            int   tj = bj[r]; bj[r] = bj[r - 1]; bj[r - 1] = tj;
          } else break;
        }
      }
    }
  }
  int* o = out_idx + ((size_t)b * NQ + s) * K;
#pragma unroll
  for (int t = 0; t < K; ++t) o[t] = bj[t];
}

// ---------------- Farthest point sampling, exact replica of reference scan.
// One block per cloud; min_d in registers, pos in LDS; 1 barrier/step via
// parity-double-buffered reduction slots.
template<int N, int M, int THREADS>
__global__ __launch_bounds__(THREADS) void fps_kernel(
    const float* __restrict__ pos, int* __restrict__ samp, float* __restrict__ pos_out)
{
  constexpr int E = N / THREADS;
  constexpr int NW = THREADS / 64;
  static_assert(E * THREADS == N, "");
  __shared__ float px[N], py[N], pz[N];
  __shared__ float rd[2][NW];
  __shared__ int   ri[2][NW];
  const int b = blockIdx.x;
  const int tid = threadIdx.x;
  const float* P = pos + (size_t)b * N * 3;
  for (int t = tid; t < N; t += THREADS) {
    px[t] = P[t * 3 + 0]; py[t] = P[t * 3 + 1]; pz[t] = P[t * 3 + 2];
  }
  __syncthreads();
  const float x0 = px[0], y0 = py[0], z0 = pz[0];
  float X[E], Y[E], Z[E], MD[E];
#pragma unroll
  for (int e = 0; e < E; ++e) {
    const int gi = e * THREADS + tid;
    X[e] = px[gi]; Y[e] = py[gi]; Z[e] = pz[gi];
    MD[e] = sqnorm3(f_sub(X[e], x0), f_sub(Y[e], y0), f_sub(Z[e], z0));
  }
  if (tid == 0) {
    samp[b * M] = 0;
    pos_out[(size_t)b * M * 3 + 0] = x0;
    pos_out[(size_t)b * M * 3 + 1] = y0;
    pos_out[(size_t)b * M * 3 + 2] = z0;
  }
  const int lane = tid & 63, wave = tid >> 6;
  for (int s = 1; s < M; ++s) {
    // local argmax (first-index tie-break: e ascending => global idx ascending)
    float bv = MD[0]; int bi = tid;
#pragma unroll
    for (int e = 1; e < E; ++e)
      if (MD[e] > bv) { bv = MD[e]; bi = e * THREADS + tid; }
    // wave butterfly argmax, tie -> smaller global index
#pragma unroll
    for (int off = 1; off < 64; off <<= 1) {
      const float ov = __shfl_xor(bv, off);
      const int   oi = __shfl_xor(bi, off);
      if (ov > bv || (ov == bv && oi < bi)) { bv = ov; bi = oi; }
    }
    const int pb = s & 1;
    if (lane == 0) { rd[pb][wave] = bv; ri[pb][wave] = bi; }
    __syncthreads();
    float gv = rd[pb][0]; int gi = ri[pb][0];
#pragma unroll
    for (int w = 1; w < NW; ++w) {
      const float v = rd[pb][w]; const int ix = ri[pb][w];
      if (v > gv || (v == gv && ix < gi)) { gv = v; gi = ix; }
    }
    const float sx = px[gi], sy = py[gi], sz = pz[gi];
    if (tid == 0) {
      samp[b * M + s] = gi;
      float* po = pos_out + ((size_t)b * M + s) * 3;
      po[0] = sx; po[1] = sy; po[2] = sz;
    }
#pragma unroll
    for (int e = 0; e < E; ++e) {
      const float d = sqnorm3(f_sub(X[e], sx), f_sub(Y[e], sy), f_sub(Z[e], sz));
      MD[e] = fminf(MD[e], d);
    }
    // no trailing barrier: next step writes the other parity slot; the barrier
    // of step s+1 separates those writes from this step's readers.
  }
}

// ---------------- PointNet edge layer: for each query point, over its K knn
// edges compute relu-MLP(2C+3 -> 32 -> 32), max-aggregate, outer relu.
template<int K, int NC, int C>
__global__ __launch_bounds__(256) void pn_layer_kernel(
    const float* __restrict__ h, const float* __restrict__ pos,
    const int* __restrict__ qidx, int NQ, const int* __restrict__ knn,
    const float* __restrict__ W1, const float* __restrict__ b1,
    const float* __restrict__ W2, const float* __restrict__ b2,
    float* __restrict__ hout)
{
  constexpr int CIN = 2 * C + 3;
  __shared__ float4 sW1[CIN * 8];
  __shared__ float4 sW2[32 * 8];
  __shared__ float sb1[32], sb2[32];
  for (int t = threadIdx.x; t < CIN * 8; t += 256) sW1[t] = ((const float4*)W1)[t];
  for (int t = threadIdx.x; t < 32 * 8; t += 256) sW2[t] = ((const float4*)W2)[t];
  if (threadIdx.x < 32) { sb1[threadIdx.x] = b1[threadIdx.x]; sb2[threadIdx.x] = b2[threadIdx.x]; }
  __syncthreads();
  const int b = blockIdx.y;
  const int s = blockIdx.x * 256 + threadIdx.x;
  const int i = qidx ? qidx[b * NQ + s] : s;
  const float* P = pos + (size_t)b * NC * 3;
  const float* H = h + (size_t)b * NC * C;
  const float xi = P[i * 3], yi = P[i * 3 + 1], zi = P[i * 3 + 2];
  float hi[C];
  if constexpr (C == 1) {
    hi[0] = H[i];
  } else {
#pragma unroll
    for (int c4 = 0; c4 < C / 4; ++c4) {
      const float4 v = ((const float4*)(H + (size_t)i * C))[c4];
      hi[4 * c4] = v.x; hi[4 * c4 + 1] = v.y; hi[4 * c4 + 2] = v.z; hi[4 * c4 + 3] = v.w;
    }
  }
  float4 best[8];
#pragma unroll
  for (int o = 0; o < 8; ++o)
    best[o] = make_float4(-__builtin_inff(), -__builtin_inff(), -__builtin_inff(), -__builtin_inff());
  const int* kn = knn + ((size_t)b * NQ + s) * K;
#pragma unroll 1
  for (int e = 0; e < K; ++e) {
    const int j = kn[e];
    const float rx = P[j * 3] - xi, ry = P[j * 3 + 1] - yi, rz = P[j * 3 + 2] - zi;
    float4 a[8];
#pragma unroll
    for (int o = 0; o < 8; ++o)
      a[o] = make_float4(sb1[4 * o], sb1[4 * o + 1], sb1[4 * o + 2], sb1[4 * o + 3]);
    // h_i block
#pragma unroll
    for (int c = 0; c < C; ++c) {
      const float v = hi[c];
#pragma unroll
      for (int o = 0; o < 8; ++o) {
        const float4 w = sW1[c * 8 + o];
        a[o].x += v * w.x; a[o].y += v * w.y; a[o].z += v * w.z; a[o].w += v * w.w;
      }
    }
    // h_j block
    if constexpr (C == 1) {
      const float v = H[j];
#pragma unroll
      for (int o = 0; o < 8; ++o) {
        const float4 w = sW1[(C + 0) * 8 + o];
        a[o].x += v * w.x; a[o].y += v * w.y; a[o].z += v * w.z; a[o].w += v * w.w;
      }
    } else {
      const float4* Hj = (const float4*)(H + (size_t)j * C);
#pragma unroll
      for (int c4 = 0; c4 < C / 4; ++c4) {
        const float4 hv = Hj[c4];
        const float vs[4] = {hv.x, hv.y, hv.z, hv.w};
#pragma unroll
        for (int q = 0; q < 4; ++q) {
          const float v = vs[q];
#pragma unroll
          for (int o = 0; o < 8; ++o) {
            const float4 w = sW1[(C + 4 * c4 + q) * 8 + o];
            a[o].x += v * w.x; a[o].y += v * w.y; a[o].z += v * w.z; a[o].w += v * w.w;
          }
        }
      }
    }
    // rel-pos block
    {
      const float rv[3] = {rx, ry, rz};
#pragma unroll
      for (int r = 0; r < 3; ++r) {
        const float v = rv[r];
#pragma unroll
        for (int o = 0; o < 8; ++o) {
          const float4 w = sW1[(2 * C + r) * 8 + o];
          a[o].x += v * w.x; a[o].y += v * w.y; a[o].z += v * w.z; a[o].w += v * w.w;
        }
      }
    }
    float u[32];
#pragma unroll
    for (int o = 0; o < 8; ++o) {
      u[4 * o]     = fmaxf(a[o].x, 0.0f);
      u[4 * o + 1] = fmaxf(a[o].y, 0.0f);
      u[4 * o + 2] = fmaxf(a[o].z, 0.0f);
      u[4 * o + 3] = fmaxf(a[o].w, 0.0f);
    }
    float4 m[8];
#pragma unroll
    for (int o = 0; o < 8; ++o)
      m[o] = make_float4(sb2[4 * o], sb2[4 * o + 1], sb2[4 * o + 2], sb2[4 * o + 3]);
#pragma unroll
    for (int c = 0; c < 32; ++c) {
      const float v = u[c];
#pragma unroll
      for (int o = 0; o < 8; ++o) {
        const float4 w = sW2[c * 8 + o];
        m[o].x += v * w.x; m[o].y += v * w.y; m[o].z += v * w.z; m[o].w += v * w.w;
      }
    }
#pragma unroll
    for (int o = 0; o < 8; ++o) {
      best[o].x = fmaxf(best[o].x, m[o].x);
      best[o].y = fmaxf(best[o].y, m[o].y);
      best[o].z = fmaxf(best[o].z, m[o].z);
      best[o].w = fmaxf(best[o].w, m[o].w);
    }
  }
  float4* ho = (float4*)(hout + ((size_t)b * NQ + s) * 32);
#pragma unroll
  for (int o = 0; o < 8; ++o)
    ho[o] = make_float4(fmaxf(best[o].x, 0.0f), fmaxf(best[o].y, 0.0f),
                        fmaxf(best[o].z, 0.0f), fmaxf(best[o].w, 0.0f));
}

// ---------------- global max pool over N3 points + final linear 32->10
__global__ __launch_bounds__(256) void final_kernel(
    const float* __restrict__ h, const float* __restrict__ Wr,
    const float* __restrict__ br, float* __restrict__ out)
{
  __shared__ float red[8][32];
  __shared__ float g[32];
  const int b = blockIdx.x;
  const int c = threadIdx.x & 31, grp = threadIdx.x >> 5;
  const float* H = h + (size_t)b * NP3 * 32;
  float m = -__builtin_inff();
  for (int r = grp; r < NP3; r += 8) m = fmaxf(m, H[r * 32 + c]);
  red[grp][c] = m;
  __syncthreads();
  if (threadIdx.x < 32) {
    float v = red[0][c];
#pragma unroll
    for (int w = 1; w < 8; ++w) v = fmaxf(v, red[w][c]);
    g[c] = v;
  }
  __syncthreads();
  if (threadIdx.x < 10) {
    float v = br[threadIdx.x];
#pragma unroll
    for (int cc = 0; cc < 32; ++cc) v += g[cc] * Wr[cc * 10 + threadIdx.x];
    out[b * 10 + threadIdx.x] = v;
  }
}

extern "C" void kernel_launch(void* const* d_in, const int* in_sizes, int n_in,
                              void* d_out, int out_size, void* d_ws, size_t ws_size,
                              hipStream_t stream) {
  const float* x   = (const float*)d_in[0];
  const float* pos = (const float*)d_in[1];
  const float* W11 = (const float*)d_in[2];
  const float* b11 = (const float*)d_in[3];
  const float* W12 = (const float*)d_in[4];
  const float* b12 = (const float*)d_in[5];
  const float* W21 = (const float*)d_in[6];
  const float* b21 = (const float*)d_in[7];
  const float* W22 = (const float*)d_in[8];
  const float* b22 = (const float*)d_in[9];
  const float* W31 = (const float*)d_in[10];
  const float* b31 = (const float*)d_in[11];
  const float* W32 = (const float*)d_in[12];
  const float* b32 = (const float*)d_in[13];
  const float* Wr  = (const float*)d_in[14];
  const float* br  = (const float*)d_in[15];
  float* out = (float*)d_out;

  char* p = (char*)d_ws;
  auto alloc = [&](size_t bytes) {
    char* r = p; p += (bytes + 255) & ~(size_t)255; return r;
  };
  int*   samp1 = (int*)  alloc(sizeof(int)   * BATCH * NP2);
  float* pos2  = (float*)alloc(sizeof(float) * BATCH * NP2 * 3);
  int*   samp2 = (int*)  alloc(sizeof(int)   * BATCH * NP3);
  float* pos3  = (float*)alloc(sizeof(float) * BATCH * NP3 * 3);
  int*   idx1  = (int*)  alloc(sizeof(int)   * BATCH * NP2 * 6);
  float* h2in  = (float*)alloc(sizeof(float) * BATCH * NP2 * 32);
  int*   idx2  = (int*)  alloc(sizeof(int)   * BATCH * NP3 * 4);
  float* h3in  = (float*)alloc(sizeof(float) * BATCH * NP3 * 32);
  int*   idx3  = (int*)  alloc(sizeof(int)   * BATCH * NP3 * 3);
  float* h3    = (float*)alloc(sizeof(float) * BATCH * NP3 * 32);

  // FPS first: sampling depends only on pos; then kNN/MLP only on sampled queries
  // (gathered row s depends only on kNN row samp[s] of the full layer).
  fps_kernel<NP1, NP2, 1024><<<BATCH, 1024, 0, stream>>>(pos, samp1, pos2);
  fps_kernel<NP2, NP3, 1024><<<BATCH, 1024, 0, stream>>>(pos2, samp2, pos3);

  knn_kernel<6, NP1><<<dim3(NP2 / 256, BATCH), 256, 0, stream>>>(pos, samp1, NP2, idx1);
  pn_layer_kernel<6, NP1, 1><<<dim3(NP2 / 256, BATCH), 256, 0, stream>>>(
      x, pos, samp1, NP2, idx1, W11, b11, W12, b12, h2in);

  knn_kernel<4, NP2><<<dim3(NP3 / 256, BATCH), 256, 0, stream>>>(pos2, samp2, NP3, idx2);
  pn_layer_kernel<4, NP2, 32><<<dim3(NP3 / 256, BATCH), 256, 0, stream>>>(
      h2in, pos2, samp2, NP3, idx2, W21, b21, W22, b22, h3in);

  knn_kernel<3, NP3><<<dim3(NP3 / 256, BATCH), 256, 0, stream>>>(pos3, nullptr, NP3, idx3);
  pn_layer_kernel<3, NP3, 32><<<dim3(NP3 / 256, BATCH), 256, 0, stream>>>(
      h3in, pos3, nullptr, NP3, idx3, W31, b31, W32, b32, h3);

  final_kernel<<<BATCH, 256, 0, stream>>>(h3, Wr, br, out);
}

// Round 2
// 6089.368 us; speedup vs baseline: 1.4468x; 1.4468x over previous
//
#include <hip/hip_runtime.h>

#define BATCH 16
#define NP1 4096
#define NP2 2048
#define NP3 1024

// IEEE ops that the compiler may NOT contract/reorder — used for every distance
// that feeds a discrete decision (kNN membership, FPS argmax). Order matches the
// reference: norms (x*x+y*y)+z*z ; knn d = (ni+nj) - 2*dot ; fps d = (dx^2+dy^2)+dz^2.
__device__ __forceinline__ float f_add(float a, float b) { return __fadd_rn(a, b); }
__device__ __forceinline__ float f_mul(float a, float b) { return __fmul_rn(a, b); }
__device__ __forceinline__ float f_sub(float a, float b) { return __fsub_rn(a, b); }
__device__ __forceinline__ float sqnorm3(float x, float y, float z) {
  return f_add(f_add(f_mul(x, x), f_mul(y, y)), f_mul(z, z));
}

// ---------------- kNN: for each query (optionally an FPS-sampled subset),
// K smallest squared distances over all NC candidates, tie -> lower index.
template<int K, int NC>
__global__ __launch_bounds__(256) void knn_kernel(
    const float* __restrict__ pos, const int* __restrict__ qidx, int NQ,
    int* __restrict__ out_idx)
{
  const int b = blockIdx.y;
  const int s = blockIdx.x * 256 + threadIdx.x;
  const int i = qidx ? qidx[b * NQ + s] : s;
  const float* P = pos + (size_t)b * NC * 3;
  const float xi = P[i * 3 + 0], yi = P[i * 3 + 1], zi = P[i * 3 + 2];
  const float ni = sqnorm3(xi, yi, zi);
  float bd[K]; int bj[K];
#pragma unroll
  for (int t = 0; t < K; ++t) { bd[t] = __builtin_inff(); bj[t] = 0; }
  __shared__ float4 tile[1024];
  for (int base = 0; base < NC; base += 1024) {
    __syncthreads();
    for (int t = threadIdx.x; t < 1024; t += 256) {
      const float* q = P + (size_t)(base + t) * 3;
      const float x = q[0], y = q[1], z = q[2];
      tile[t] = make_float4(x, y, z, sqnorm3(x, y, z));
    }
    __syncthreads();
#pragma unroll 2
    for (int t = 0; t < 1024; ++t) {
      const float4 q = tile[t];
      const float dot = f_add(f_add(f_mul(xi, q.x), f_mul(yi, q.y)), f_mul(zi, q.z));
      const float d = f_sub(f_add(ni, q.w), f_mul(2.0f, dot));
      if (d < bd[K - 1]) {          // strict < keeps earlier index on ties
        bd[K - 1] = d; bj[K - 1] = base + t;
#pragma unroll
        for (int r = K - 1; r > 0; --r) {
          if (bd[r] < bd[r - 1]) {  // strict < : equal values keep insertion (index) order
            float td = bd[r]; bd[r] = bd[r - 1]; bd[r - 1] = td;
            int   tj = bj[r]; bj[r] = bj[r - 1]; bj[r - 1] = tj;
          } else break;
        }
      }
    }
  }
  int* o = out_idx + ((size_t)b * NQ + s) * K;
#pragma unroll
  for (int t = 0; t < K; ++t) o[t] = bj[t];
}

// ---------------- Farthest point sampling, exact replica of reference scan.
// One block per cloud. Latency-optimized:
//  - (dist,idx) packed into a single sortable u64 key: dists are non-negative
//    IEEE floats (bit pattern is order-monotone); low word = 0xFFFFFFFF - idx
//    so u64-max gives max dist, ties -> smallest index (== jnp.argmax).
//  - local argmax is FUSED into the MD-update loop (one less dependent pass).
//  - cross-wave: 16 u64 slots, parity double-buffered (1 barrier/step),
//    tree-reduced in registers (depth 4, not a serial 16-chain).
template<int N, int M, int THREADS>
__global__ __launch_bounds__(THREADS) void fps_kernel(
    const float* __restrict__ pos, int* __restrict__ samp, float* __restrict__ pos_out)
{
  constexpr int E = N / THREADS;
  constexpr int NW = THREADS / 64;
  static_assert(E * THREADS == N, "");
  __shared__ float px[N], py[N], pz[N];
  __shared__ unsigned long long slots[2][NW];
  const int b = blockIdx.x;
  const int tid = threadIdx.x;
  const float* P = pos + (size_t)b * N * 3;
  for (int t = tid; t < N; t += THREADS) {
    px[t] = P[t * 3 + 0]; py[t] = P[t * 3 + 1]; pz[t] = P[t * 3 + 2];
  }
  __syncthreads();
  const float x0 = px[0], y0 = py[0], z0 = pz[0];
  float X[E], Y[E], Z[E], MD[E];
  unsigned long long key = 0;
#pragma unroll
  for (int e = 0; e < E; ++e) {
    const int gi = e * THREADS + tid;
    X[e] = px[gi]; Y[e] = py[gi]; Z[e] = pz[gi];
    MD[e] = sqnorm3(f_sub(X[e], x0), f_sub(Y[e], y0), f_sub(Z[e], z0));
    const unsigned long long k =
        ((unsigned long long)__float_as_uint(MD[e]) << 32) | (unsigned)(0xFFFFFFFFu - gi);
    key = key > k ? key : k;
  }
  if (tid == 0) {
    samp[b * M] = 0;
    pos_out[(size_t)b * M * 3 + 0] = x0;
    pos_out[(size_t)b * M * 3 + 1] = y0;
    pos_out[(size_t)b * M * 3 + 2] = z0;
  }
  const int lane = tid & 63, wave = tid >> 6;
  for (int s = 1; s < M; ++s) {
    // wave butterfly max on the packed key (2x 32-bit shuffles per hop)
#pragma unroll
    for (int off = 1; off < 64; off <<= 1) {
      const unsigned lo = (unsigned)key, hi = (unsigned)(key >> 32);
      const unsigned olo = __shfl_xor(lo, off);
      const unsigned ohi = __shfl_xor(hi, off);
      const unsigned long long o = ((unsigned long long)ohi << 32) | olo;
      key = o > key ? o : key;
    }
    const int pb = s & 1;
    if (lane == 0) slots[pb][wave] = key;
    __syncthreads();
    unsigned long long v[NW];
#pragma unroll
    for (int w = 0; w < NW; ++w) v[w] = slots[pb][w];
#pragma unroll
    for (int st = NW / 2; st > 0; st >>= 1)
#pragma unroll
      for (int w = 0; w < st; ++w) v[w] = v[w] > v[w + st] ? v[w] : v[w + st];
    const int gi = (int)(0xFFFFFFFFu - (unsigned)v[0]);
    const float sx = px[gi], sy = py[gi], sz = pz[gi];
    if (tid == 0) {
      samp[b * M + s] = gi;
      float* po = pos_out + ((size_t)b * M + s) * 3;
      po[0] = sx; po[1] = sy; po[2] = sz;
    }
    key = 0;
#pragma unroll
    for (int e = 0; e < E; ++e) {
      const float d = sqnorm3(f_sub(X[e], sx), f_sub(Y[e], sy), f_sub(Z[e], sz));
      MD[e] = fminf(MD[e], d);
      const unsigned long long k =
          ((unsigned long long)__float_as_uint(MD[e]) << 32) |
          (unsigned)(0xFFFFFFFFu - (e * THREADS + tid));
      key = key > k ? key : k;
    }
    // no trailing barrier: next step writes the other parity slot; the barrier
    // of step s+1 separates those writes from this step's readers.
  }
}

// ---------------- PointNet edge layer: for each query point, over its K knn
// edges compute relu-MLP(2C+3 -> 32 -> 32), max-aggregate, outer relu.
template<int K, int NC, int C>
__global__ __launch_bounds__(256) void pn_layer_kernel(
    const float* __restrict__ h, const float* __restrict__ pos,
    const int* __restrict__ qidx, int NQ, const int* __restrict__ knn,
    const float* __restrict__ W1, const float* __restrict__ b1,
    const float* __restrict__ W2, const float* __restrict__ b2,
    float* __restrict__ hout)
{
  constexpr int CIN = 2 * C + 3;
  __shared__ float4 sW1[CIN * 8];
  __shared__ float4 sW2[32 * 8];
  __shared__ float sb1[32], sb2[32];
  for (int t = threadIdx.x; t < CIN * 8; t += 256) sW1[t] = ((const float4*)W1)[t];
  for (int t = threadIdx.x; t < 32 * 8; t += 256) sW2[t] = ((const float4*)W2)[t];
  if (threadIdx.x < 32) { sb1[threadIdx.x] = b1[threadIdx.x]; sb2[threadIdx.x] = b2[threadIdx.x]; }
  __syncthreads();
  const int b = blockIdx.y;
  const int s = blockIdx.x * 256 + threadIdx.x;
  const int i = qidx ? qidx[b * NQ + s] : s;
  const float* P = pos + (size_t)b * NC * 3;
  const float* H = h + (size_t)b * NC * C;
  const float xi = P[i * 3], yi = P[i * 3 + 1], zi = P[i * 3 + 2];
  float hi[C];
  if constexpr (C == 1) {
    hi[0] = H[i];
  } else {
#pragma unroll
    for (int c4 = 0; c4 < C / 4; ++c4) {
      const float4 v = ((const float4*)(H + (size_t)i * C))[c4];
      hi[4 * c4] = v.x; hi[4 * c4 + 1] = v.y; hi[4 * c4 + 2] = v.z; hi[4 * c4 + 3] = v.w;
    }
  }
  float4 best[8];
#pragma unroll
  for (int o = 0; o < 8; ++o)
    best[o] = make_float4(-__builtin_inff(), -__builtin_inff(), -__builtin_inff(), -__builtin_inff());
  const int* kn = knn + ((size_t)b * NQ + s) * K;
#pragma unroll 1
  for (int e = 0; e < K; ++e) {
    const int j = kn[e];
    const float rx = P[j * 3] - xi, ry = P[j * 3 + 1] - yi, rz = P[j * 3 + 2] - zi;
    float4 a[8];
#pragma unroll
    for (int o = 0; o < 8; ++o)
      a[o] = make_float4(sb1[4 * o], sb1[4 * o + 1], sb1[4 * o + 2], sb1[4 * o + 3]);
    // h_i block
#pragma unroll
    for (int c = 0; c < C; ++c) {
      const float v = hi[c];
#pragma unroll
      for (int o = 0; o < 8; ++o) {
        const float4 w = sW1[c * 8 + o];
        a[o].x += v * w.x; a[o].y += v * w.y; a[o].z += v * w.z; a[o].w += v * w.w;
      }
    }
    // h_j block
    if constexpr (C == 1) {
      const float v = H[j];
#pragma unroll
      for (int o = 0; o < 8; ++o) {
        const float4 w = sW1[(C + 0) * 8 + o];
        a[o].x += v * w.x; a[o].y += v * w.y; a[o].z += v * w.z; a[o].w += v * w.w;
      }
    } else {
      const float4* Hj = (const float4*)(H + (size_t)j * C);
#pragma unroll
      for (int c4 = 0; c4 < C / 4; ++c4) {
        const float4 hv = Hj[c4];
        const float vs[4] = {hv.x, hv.y, hv.z, hv.w};
#pragma unroll
        for (int q = 0; q < 4; ++q) {
          const float v = vs[q];
#pragma unroll
          for (int o = 0; o < 8; ++o) {
            const float4 w = sW1[(C + 4 * c4 + q) * 8 + o];
            a[o].x += v * w.x; a[o].y += v * w.y; a[o].z += v * w.z; a[o].w += v * w.w;
          }
        }
      }
    }
    // rel-pos block
    {
      const float rv[3] = {rx, ry, rz};
#pragma unroll
      for (int r = 0; r < 3; ++r) {
        const float v = rv[r];
#pragma unroll
        for (int o = 0; o < 8; ++o) {
          const float4 w = sW1[(2 * C + r) * 8 + o];
          a[o].x += v * w.x; a[o].y += v * w.y; a[o].z += v * w.z; a[o].w += v * w.w;
        }
      }
    }
    float u[32];
#pragma unroll
    for (int o = 0; o < 8; ++o) {
      u[4 * o]     = fmaxf(a[o].x, 0.0f);
      u[4 * o + 1] = fmaxf(a[o].y, 0.0f);
      u[4 * o + 2] = fmaxf(a[o].z, 0.0f);
      u[4 * o + 3] = fmaxf(a[o].w, 0.0f);
    }
    float4 m[8];
#pragma unroll
    for (int o = 0; o < 8; ++o)
      m[o] = make_float4(sb2[4 * o], sb2[4 * o + 1], sb2[4 * o + 2], sb2[4 * o + 3]);
#pragma unroll
    for (int c = 0; c < 32; ++c) {
      const float v = u[c];
#pragma unroll
      for (int o = 0; o < 8; ++o) {
        const float4 w = sW2[c * 8 + o];
        m[o].x += v * w.x; m[o].y += v * w.y; m[o].z += v * w.z; m[o].w += v * w.w;
      }
    }
#pragma unroll
    for (int o = 0; o < 8; ++o) {
      best[o].x = fmaxf(best[o].x, m[o].x);
      best[o].y = fmaxf(best[o].y, m[o].y);
      best[o].z = fmaxf(best[o].z, m[o].z);
      best[o].w = fmaxf(best[o].w, m[o].w);
    }
  }
  float4* ho = (float4*)(hout + ((size_t)b * NQ + s) * 32);
#pragma unroll
  for (int o = 0; o < 8; ++o)
    ho[o] = make_float4(fmaxf(best[o].x, 0.0f), fmaxf(best[o].y, 0.0f),
                        fmaxf(best[o].z, 0.0f), fmaxf(best[o].w, 0.0f));
}

// ---------------- global max pool over N3 points + final linear 32->10
__global__ __launch_bounds__(256) void final_kernel(
    const float* __restrict__ h, const float* __restrict__ Wr,
    const float* __restrict__ br, float* __restrict__ out)
{
  __shared__ float red[8][32];
  __shared__ float g[32];
  const int b = blockIdx.x;
  const int c = threadIdx.x & 31, grp = threadIdx.x >> 5;
  const float* H = h + (size_t)b * NP3 * 32;
  float m = -__builtin_inff();
  for (int r = grp; r < NP3; r += 8) m = fmaxf(m, H[r * 32 + c]);
  red[grp][c] = m;
  __syncthreads();
  if (threadIdx.x < 32) {
    float v = red[0][c];
#pragma unroll
    for (int w = 1; w < 8; ++w) v = fmaxf(v, red[w][c]);
    g[c] = v;
  }
  __syncthreads();
  if (threadIdx.x < 10) {
    float v = br[threadIdx.x];
#pragma unroll
    for (int cc = 0; cc < 32; ++cc) v += g[cc] * Wr[cc * 10 + threadIdx.x];
    out[b * 10 + threadIdx.x] = v;
  }
}

extern "C" void kernel_launch(void* const* d_in, const int* in_sizes, int n_in,
                              void* d_out, int out_size, void* d_ws, size_t ws_size,
                              hipStream_t stream) {
  const float* x   = (const float*)d_in[0];
  const float* pos = (const float*)d_in[1];
  const float* W11 = (const float*)d_in[2];
  const float* b11 = (const float*)d_in[3];
  const float* W12 = (const float*)d_in[4];
  const float* b12 = (const float*)d_in[5];
  const float* W21 = (const float*)d_in[6];
  const float* b21 = (const float*)d_in[7];
  const float* W22 = (const float*)d_in[8];
  const float* b22 = (const float*)d_in[9];
  const float* W31 = (const float*)d_in[10];
  const float* b31 = (const float*)d_in[11];
  const float* W32 = (const float*)d_in[12];
  const float* b32 = (const float*)d_in[13];
  const float* Wr  = (const float*)d_in[14];
  const float* br  = (const float*)d_in[15];
  float* out = (float*)d_out;

  char* p = (char*)d_ws;
  auto alloc = [&](size_t bytes) {
    char* r = p; p += (bytes + 255) & ~(size_t)255; return r;
  };
  int*   samp1 = (int*)  alloc(sizeof(int)   * BATCH * NP2);
  float* pos2  = (float*)alloc(sizeof(float) * BATCH * NP2 * 3);
  int*   samp2 = (int*)  alloc(sizeof(int)   * BATCH * NP3);
  float* pos3  = (float*)alloc(sizeof(float) * BATCH * NP3 * 3);
  int*   idx1  = (int*)  alloc(sizeof(int)   * BATCH * NP2 * 6);
  float* h2in  = (float*)alloc(sizeof(float) * BATCH * NP2 * 32);
  int*   idx2  = (int*)  alloc(sizeof(int)   * BATCH * NP3 * 4);
  float* h3in  = (float*)alloc(sizeof(float) * BATCH * NP3 * 32);
  int*   idx3  = (int*)  alloc(sizeof(int)   * BATCH * NP3 * 3);
  float* h3    = (float*)alloc(sizeof(float) * BATCH * NP3 * 32);

  // FPS first: sampling depends only on pos; then kNN/MLP only on sampled queries
  // (gathered row s depends only on kNN row samp[s] of the full layer).
  fps_kernel<NP1, NP2, 1024><<<BATCH, 1024, 0, stream>>>(pos, samp1, pos2);
  fps_kernel<NP2, NP3, 1024><<<BATCH, 1024, 0, stream>>>(pos2, samp2, pos3);

  knn_kernel<6, NP1><<<dim3(NP2 / 256, BATCH), 256, 0, stream>>>(pos, samp1, NP2, idx1);
  pn_layer_kernel<6, NP1, 1><<<dim3(NP2 / 256, BATCH), 256, 0, stream>>>(
      x, pos, samp1, NP2, idx1, W11, b11, W12, b12, h2in);

  knn_kernel<4, NP2><<<dim3(NP3 / 256, BATCH), 256, 0, stream>>>(pos2, samp2, NP3, idx2);
  pn_layer_kernel<4, NP2, 32><<<dim3(NP3 / 256, BATCH), 256, 0, stream>>>(
      h2in, pos2, samp2, NP3, idx2, W21, b21, W22, b22, h3in);

  knn_kernel<3, NP3><<<dim3(NP3 / 256, BATCH), 256, 0, stream>>>(pos3, nullptr, NP3, idx3);
  pn_layer_kernel<3, NP3, 32><<<dim3(NP3 / 256, BATCH), 256, 0, stream>>>(
      h3in, pos3, nullptr, NP3, idx3, W31, b31, W32, b32, h3);

  final_kernel<<<BATCH, 256, 0, stream>>>(h3, Wr, br, out);
}

// Round 3
// 4885.487 us; speedup vs baseline: 1.8033x; 1.2464x over previous
//
#include <hip/hip_runtime.h>

#define BATCH 16
#define NP1 4096
#define NP2 2048
#define NP3 1024

// IEEE ops that the compiler may NOT contract/reorder — used for every distance
// that feeds a discrete decision (kNN membership, FPS argmax). Order matches the
// reference: norms (x*x+y*y)+z*z ; knn d = (ni+nj) - 2*dot ; fps d = (dx^2+dy^2)+dz^2.
__device__ __forceinline__ float f_add(float a, float b) { return __fadd_rn(a, b); }
__device__ __forceinline__ float f_mul(float a, float b) { return __fmul_rn(a, b); }
__device__ __forceinline__ float f_sub(float a, float b) { return __fsub_rn(a, b); }
__device__ __forceinline__ float sqnorm3(float x, float y, float z) {
  return f_add(f_add(f_mul(x, x), f_mul(y, y)), f_mul(z, z));
}

__device__ __forceinline__ unsigned long long u64max(unsigned long long a,
                                                     unsigned long long b) {
  return a > b ? a : b;
}

// DPP-shifted copy of a u64 (two 32-bit halves), invalid lanes -> 0 (identity for
// our keys, which are always > 0).
template<int CTRL, int RMASK>
__device__ __forceinline__ unsigned long long dpp_u64(unsigned long long k) {
  const int lo = __builtin_amdgcn_update_dpp(0, (int)(unsigned)k, CTRL, RMASK, 0xF, true);
  const int hi = __builtin_amdgcn_update_dpp(0, (int)(unsigned)(k >> 32), CTRL, RMASK, 0xF, true);
  return ((unsigned long long)(unsigned)hi << 32) | (unsigned)lo;
}

// Wave64 max-reduce of the packed key into lane 63.
// row_shr:k = 0x110|k, row_bcast15 = 0x142 (rows 1,3), row_bcast31 = 0x143 (rows 2,3).
__device__ __forceinline__ unsigned long long wave_max_key(unsigned long long k) {
  k = u64max(k, dpp_u64<0x111, 0xF>(k));
  k = u64max(k, dpp_u64<0x112, 0xF>(k));
  k = u64max(k, dpp_u64<0x114, 0xF>(k));
  k = u64max(k, dpp_u64<0x118, 0xF>(k));
  k = u64max(k, dpp_u64<0x142, 0xA>(k));
  k = u64max(k, dpp_u64<0x143, 0xC>(k));
  return k;
}

// ---------------- kNN: for each query (optionally an FPS-sampled subset),
// K smallest squared distances over all NC candidates, tie -> lower index.
template<int K, int NC>
__global__ __launch_bounds__(256) void knn_kernel(
    const float* __restrict__ pos, const int* __restrict__ qidx, int NQ,
    int* __restrict__ out_idx)
{
  const int b = blockIdx.y;
  const int s = blockIdx.x * 256 + threadIdx.x;
  const int i = qidx ? qidx[b * NQ + s] : s;
  const float* P = pos + (size_t)b * NC * 3;
  const float xi = P[i * 3 + 0], yi = P[i * 3 + 1], zi = P[i * 3 + 2];
  const float ni = sqnorm3(xi, yi, zi);
  float bd[K]; int bj[K];
#pragma unroll
  for (int t = 0; t < K; ++t) { bd[t] = __builtin_inff(); bj[t] = 0; }
  __shared__ float4 tile[1024];
  for (int base = 0; base < NC; base += 1024) {
    __syncthreads();
    for (int t = threadIdx.x; t < 1024; t += 256) {
      const float* q = P + (size_t)(base + t) * 3;
      const float x = q[0], y = q[1], z = q[2];
      tile[t] = make_float4(x, y, z, sqnorm3(x, y, z));
    }
    __syncthreads();
#pragma unroll 2
    for (int t = 0; t < 1024; ++t) {
      const float4 q = tile[t];
      const float dot = f_add(f_add(f_mul(xi, q.x), f_mul(yi, q.y)), f_mul(zi, q.z));
      const float d = f_sub(f_add(ni, q.w), f_mul(2.0f, dot));
      if (d < bd[K - 1]) {          // strict < keeps earlier index on ties
        bd[K - 1] = d; bj[K - 1] = base + t;
#pragma unroll
        for (int r = K - 1; r > 0; --r) {
          if (bd[r] < bd[r - 1]) {  // strict < : equal values keep insertion (index) order
            float td = bd[r]; bd[r] = bd[r - 1]; bd[r - 1] = td;
            int   tj = bj[r]; bj[r] = bj[r - 1]; bj[r - 1] = tj;
          } else break;
        }
      }
    }
  }
  int* o = out_idx + ((size_t)b * NQ + s) * K;
#pragma unroll
  for (int t = 0; t < K; ++t) o[t] = bj[t];
}

// ---------------- Farthest point sampling, exact replica of reference scan.
// One block per cloud. Latency-optimized:
//  - (dist,idx) packed into one sortable u64: non-negative IEEE float bits are
//    order-monotone; low word = 0xFFFFFFFF - idx so max => smallest idx on ties.
//  - wave reduce via DPP (row_shr/row_bcast) — VALU pipe, no LDS round trips.
//  - cross-wave: ONE ds_max_u64 atomic per wave into a single LDS slot;
//    3-slot rotation so the reset of the previous slot is barrier-ordered
//    against both its last readers (step s-1, before barrier s) and its next
//    writers (step s+2, after barrier s+1). 1 barrier per step.
template<int N, int M, int THREADS>
__global__ __launch_bounds__(THREADS) void fps_kernel(
    const float* __restrict__ pos, int* __restrict__ samp, float* __restrict__ pos_out)
{
  constexpr int E = N / THREADS;
  static_assert(E * THREADS == N, "");
  __shared__ float px[N], py[N], pz[N];
  __shared__ unsigned long long slot[3];
  const int b = blockIdx.x;
  const int tid = threadIdx.x;
  const float* P = pos + (size_t)b * N * 3;
  for (int t = tid; t < N; t += THREADS) {
    px[t] = P[t * 3 + 0]; py[t] = P[t * 3 + 1]; pz[t] = P[t * 3 + 2];
  }
  if (tid < 3) slot[tid] = 0ull;
  __syncthreads();
  const float x0 = px[0], y0 = py[0], z0 = pz[0];
  float X[E], Y[E], Z[E], MD[E];
  unsigned ILO[E];
  unsigned long long key = 0;
#pragma unroll
  for (int e = 0; e < E; ++e) {
    const int gi = e * THREADS + tid;
    X[e] = px[gi]; Y[e] = py[gi]; Z[e] = pz[gi];
    MD[e] = sqnorm3(f_sub(X[e], x0), f_sub(Y[e], y0), f_sub(Z[e], z0));
    ILO[e] = 0xFFFFFFFFu - (unsigned)gi;
    key = u64max(key, ((unsigned long long)__float_as_uint(MD[e]) << 32) | ILO[e]);
  }
  if (tid == 0) {
    samp[b * M] = 0;
    pos_out[(size_t)b * M * 3 + 0] = x0;
    pos_out[(size_t)b * M * 3 + 1] = y0;
    pos_out[(size_t)b * M * 3 + 2] = z0;
  }
  const int lane = tid & 63;
  int cur = 1;  // slot index = s % 3
#pragma unroll 1
  for (int s = 1; s < M; ++s) {
    const unsigned long long wk = wave_max_key(key);
    if (lane == 63) atomicMax(&slot[cur], wk);
    __syncthreads();
    const unsigned long long w = slot[cur];
    const int gi = (int)(0xFFFFFFFFu - (unsigned)w);
    const float sx = px[gi], sy = py[gi], sz = pz[gi];
    // reset the PREVIOUS slot (last read at step s-1, next written at step s+2)
    const int prev = cur == 0 ? 2 : cur - 1;
    if (tid == 0) {
      slot[prev] = 0ull;
      samp[b * M + s] = gi;
      float* po = pos_out + ((size_t)b * M + s) * 3;
      po[0] = sx; po[1] = sy; po[2] = sz;
    }
    cur = cur == 2 ? 0 : cur + 1;
    key = 0;
#pragma unroll
    for (int e = 0; e < E; ++e) {
      const float d = sqnorm3(f_sub(X[e], sx), f_sub(Y[e], sy), f_sub(Z[e], sz));
      MD[e] = fminf(MD[e], d);
      key = u64max(key, ((unsigned long long)__float_as_uint(MD[e]) << 32) | ILO[e]);
    }
  }
}

// ---------------- PointNet edge layer: for each query point, over its K knn
// edges compute relu-MLP(2C+3 -> 32 -> 32), max-aggregate, outer relu.
template<int K, int NC, int C>
__global__ __launch_bounds__(256) void pn_layer_kernel(
    const float* __restrict__ h, const float* __restrict__ pos,
    const int* __restrict__ qidx, int NQ, const int* __restrict__ knn,
    const float* __restrict__ W1, const float* __restrict__ b1,
    const float* __restrict__ W2, const float* __restrict__ b2,
    float* __restrict__ hout)
{
  constexpr int CIN = 2 * C + 3;
  __shared__ float4 sW1[CIN * 8];
  __shared__ float4 sW2[32 * 8];
  __shared__ float sb1[32], sb2[32];
  for (int t = threadIdx.x; t < CIN * 8; t += 256) sW1[t] = ((const float4*)W1)[t];
  for (int t = threadIdx.x; t < 32 * 8; t += 256) sW2[t] = ((const float4*)W2)[t];
  if (threadIdx.x < 32) { sb1[threadIdx.x] = b1[threadIdx.x]; sb2[threadIdx.x] = b2[threadIdx.x]; }
  __syncthreads();
  const int b = blockIdx.y;
  const int s = blockIdx.x * 256 + threadIdx.x;
  const int i = qidx ? qidx[b * NQ + s] : s;
  const float* P = pos + (size_t)b * NC * 3;
  const float* H = h + (size_t)b * NC * C;
  const float xi = P[i * 3], yi = P[i * 3 + 1], zi = P[i * 3 + 2];
  float hi[C];
  if constexpr (C == 1) {
    hi[0] = H[i];
  } else {
#pragma unroll
    for (int c4 = 0; c4 < C / 4; ++c4) {
      const float4 v = ((const float4*)(H + (size_t)i * C))[c4];
      hi[4 * c4] = v.x; hi[4 * c4 + 1] = v.y; hi[4 * c4 + 2] = v.z; hi[4 * c4 + 3] = v.w;
    }
  }
  float4 best[8];
#pragma unroll
  for (int o = 0; o < 8; ++o)
    best[o] = make_float4(-__builtin_inff(), -__builtin_inff(), -__builtin_inff(), -__builtin_inff());
  const int* kn = knn + ((size_t)b * NQ + s) * K;
#pragma unroll 1
  for (int e = 0; e < K; ++e) {
    const int j = kn[e];
    const float rx = P[j * 3] - xi, ry = P[j * 3 + 1] - yi, rz = P[j * 3 + 2] - zi;
    float4 a[8];
#pragma unroll
    for (int o = 0; o < 8; ++o)
      a[o] = make_float4(sb1[4 * o], sb1[4 * o + 1], sb1[4 * o + 2], sb1[4 * o + 3]);
    // h_i block
#pragma unroll
    for (int c = 0; c < C; ++c) {
      const float v = hi[c];
#pragma unroll
      for (int o = 0; o < 8; ++o) {
        const float4 w = sW1[c * 8 + o];
        a[o].x += v * w.x; a[o].y += v * w.y; a[o].z += v * w.z; a[o].w += v * w.w;
      }
    }
    // h_j block
    if constexpr (C == 1) {
      const float v = H[j];
#pragma unroll
      for (int o = 0; o < 8; ++o) {
        const float4 w = sW1[(C + 0) * 8 + o];
        a[o].x += v * w.x; a[o].y += v * w.y; a[o].z += v * w.z; a[o].w += v * w.w;
      }
    } else {
      const float4* Hj = (const float4*)(H + (size_t)j * C);
#pragma unroll
      for (int c4 = 0; c4 < C / 4; ++c4) {
        const float4 hv = Hj[c4];
        const float vs[4] = {hv.x, hv.y, hv.z, hv.w};
#pragma unroll
        for (int q = 0; q < 4; ++q) {
          const float v = vs[q];
#pragma unroll
          for (int o = 0; o < 8; ++o) {
            const float4 w = sW1[(C + 4 * c4 + q) * 8 + o];
            a[o].x += v * w.x; a[o].y += v * w.y; a[o].z += v * w.z; a[o].w += v * w.w;
          }
        }
      }
    }
    // rel-pos block
    {
      const float rv[3] = {rx, ry, rz};
#pragma unroll
      for (int r = 0; r < 3; ++r) {
        const float v = rv[r];
#pragma unroll
        for (int o = 0; o < 8; ++o) {
          const float4 w = sW1[(2 * C + r) * 8 + o];
          a[o].x += v * w.x; a[o].y += v * w.y; a[o].z += v * w.z; a[o].w += v * w.w;
        }
      }
    }
    float u[32];
#pragma unroll
    for (int o = 0; o < 8; ++o) {
      u[4 * o]     = fmaxf(a[o].x, 0.0f);
      u[4 * o + 1] = fmaxf(a[o].y, 0.0f);
      u[4 * o + 2] = fmaxf(a[o].z, 0.0f);
      u[4 * o + 3] = fmaxf(a[o].w, 0.0f);
    }
    float4 m[8];
#pragma unroll
    for (int o = 0; o < 8; ++o)
      m[o] = make_float4(sb2[4 * o], sb2[4 * o + 1], sb2[4 * o + 2], sb2[4 * o + 3]);
#pragma unroll
    for (int c = 0; c < 32; ++c) {
      const float v = u[c];
#pragma unroll
      for (int o = 0; o < 8; ++o) {
        const float4 w = sW2[c * 8 + o];
        m[o].x += v * w.x; m[o].y += v * w.y; m[o].z += v * w.z; m[o].w += v * w.w;
      }
    }
#pragma unroll
    for (int o = 0; o < 8; ++o) {
      best[o].x = fmaxf(best[o].x, m[o].x);
      best[o].y = fmaxf(best[o].y, m[o].y);
      best[o].z = fmaxf(best[o].z, m[o].z);
      best[o].w = fmaxf(best[o].w, m[o].w);
    }
  }
  float4* ho = (float4*)(hout + ((size_t)b * NQ + s) * 32);
#pragma unroll
  for (int o = 0; o < 8; ++o)
    ho[o] = make_float4(fmaxf(best[o].x, 0.0f), fmaxf(best[o].y, 0.0f),
                        fmaxf(best[o].z, 0.0f), fmaxf(best[o].w, 0.0f));
}

// ---------------- global max pool over N3 points + final linear 32->10
__global__ __launch_bounds__(256) void final_kernel(
    const float* __restrict__ h, const float* __restrict__ Wr,
    const float* __restrict__ br, float* __restrict__ out)
{
  __shared__ float red[8][32];
  __shared__ float g[32];
  const int b = blockIdx.x;
  const int c = threadIdx.x & 31, grp = threadIdx.x >> 5;
  const float* H = h + (size_t)b * NP3 * 32;
  float m = -__builtin_inff();
  for (int r = grp; r < NP3; r += 8) m = fmaxf(m, H[r * 32 + c]);
  red[grp][c] = m;
  __syncthreads();
  if (threadIdx.x < 32) {
    float v = red[0][c];
#pragma unroll
    for (int w = 1; w < 8; ++w) v = fmaxf(v, red[w][c]);
    g[c] = v;
  }
  __syncthreads();
  if (threadIdx.x < 10) {
    float v = br[threadIdx.x];
#pragma unroll
    for (int cc = 0; cc < 32; ++cc) v += g[cc] * Wr[cc * 10 + threadIdx.x];
    out[b * 10 + threadIdx.x] = v;
  }
}

extern "C" void kernel_launch(void* const* d_in, const int* in_sizes, int n_in,
                              void* d_out, int out_size, void* d_ws, size_t ws_size,
                              hipStream_t stream) {
  const float* x   = (const float*)d_in[0];
  const float* pos = (const float*)d_in[1];
  const float* W11 = (const float*)d_in[2];
  const float* b11 = (const float*)d_in[3];
  const float* W12 = (const float*)d_in[4];
  const float* b12 = (const float*)d_in[5];
  const float* W21 = (const float*)d_in[6];
  const float* b21 = (const float*)d_in[7];
  const float* W22 = (const float*)d_in[8];
  const float* b22 = (const float*)d_in[9];
  const float* W31 = (const float*)d_in[10];
  const float* b31 = (const float*)d_in[11];
  const float* W32 = (const float*)d_in[12];
  const float* b32 = (const float*)d_in[13];
  const float* Wr  = (const float*)d_in[14];
  const float* br  = (const float*)d_in[15];
  float* out = (float*)d_out;

  char* p = (char*)d_ws;
  auto alloc = [&](size_t bytes) {
    char* r = p; p += (bytes + 255) & ~(size_t)255; return r;
  };
  int*   samp1 = (int*)  alloc(sizeof(int)   * BATCH * NP2);
  float* pos2  = (float*)alloc(sizeof(float) * BATCH * NP2 * 3);
  int*   samp2 = (int*)  alloc(sizeof(int)   * BATCH * NP3);
  float* pos3  = (float*)alloc(sizeof(float) * BATCH * NP3 * 3);
  int*   idx1  = (int*)  alloc(sizeof(int)   * BATCH * NP2 * 6);
  float* h2in  = (float*)alloc(sizeof(float) * BATCH * NP2 * 32);
  int*   idx2  = (int*)  alloc(sizeof(int)   * BATCH * NP3 * 4);
  float* h3in  = (float*)alloc(sizeof(float) * BATCH * NP3 * 32);
  int*   idx3  = (int*)  alloc(sizeof(int)   * BATCH * NP3 * 3);
  float* h3    = (float*)alloc(sizeof(float) * BATCH * NP3 * 32);

  // FPS first: sampling depends only on pos; then kNN/MLP only on sampled queries
  // (gathered row s depends only on kNN row samp[s] of the full layer).
  fps_kernel<NP1, NP2, 1024><<<BATCH, 1024, 0, stream>>>(pos, samp1, pos2);
  fps_kernel<NP2, NP3, 1024><<<BATCH, 1024, 0, stream>>>(pos2, samp2, pos3);

  knn_kernel<6, NP1><<<dim3(NP2 / 256, BATCH), 256, 0, stream>>>(pos, samp1, NP2, idx1);
  pn_layer_kernel<6, NP1, 1><<<dim3(NP2 / 256, BATCH), 256, 0, stream>>>(
      x, pos, samp1, NP2, idx1, W11, b11, W12, b12, h2in);

  knn_kernel<4, NP2><<<dim3(NP3 / 256, BATCH), 256, 0, stream>>>(pos2, samp2, NP3, idx2);
  pn_layer_kernel<4, NP2, 32><<<dim3(NP3 / 256, BATCH), 256, 0, stream>>>(
      h2in, pos2, samp2, NP3, idx2, W21, b21, W22, b22, h3in);

  knn_kernel<3, NP3><<<dim3(NP3 / 256, BATCH), 256, 0, stream>>>(pos3, nullptr, NP3, idx3);
  pn_layer_kernel<3, NP3, 32><<<dim3(NP3 / 256, BATCH), 256, 0, stream>>>(
      h3in, pos3, nullptr, NP3, idx3, W31, b31, W32, b32, h3);

  final_kernel<<<BATCH, 256, 0, stream>>>(h3, Wr, br, out);
}

// Round 4
// 2790.136 us; speedup vs baseline: 3.1575x; 1.7510x over previous
//
#include <hip/hip_runtime.h>

#define BATCH 16
#define NP1 4096
#define NP2 2048
#define NP3 1024

typedef float v2f __attribute__((ext_vector_type(2)));

// IEEE ops that the compiler may NOT contract/reorder — used for every distance
// that feeds a discrete decision (kNN membership, FPS argmax). Order matches the
// reference: norms (x*x+y*y)+z*z ; knn d = (ni+nj) - 2*dot ; fps d = (dx^2+dy^2)+dz^2.
__device__ __forceinline__ float f_add(float a, float b) { return __fadd_rn(a, b); }
__device__ __forceinline__ float f_mul(float a, float b) { return __fmul_rn(a, b); }
__device__ __forceinline__ float f_sub(float a, float b) { return __fsub_rn(a, b); }
__device__ __forceinline__ float sqnorm3(float x, float y, float z) {
  return f_add(f_add(f_mul(x, x), f_mul(y, y)), f_mul(z, z));
}

__device__ __forceinline__ unsigned long long u64max(unsigned long long a,
                                                     unsigned long long b) {
  return a > b ? a : b;
}

// DPP-shifted copy of a u64 (two 32-bit halves), invalid lanes -> 0 (identity for
// our keys, which are always > 0).
template<int CTRL, int RMASK>
__device__ __forceinline__ unsigned long long dpp_u64(unsigned long long k) {
  const int lo = __builtin_amdgcn_update_dpp(0, (int)(unsigned)k, CTRL, RMASK, 0xF, true);
  const int hi = __builtin_amdgcn_update_dpp(0, (int)(unsigned)(k >> 32), CTRL, RMASK, 0xF, true);
  return ((unsigned long long)(unsigned)hi << 32) | (unsigned)lo;
}

// Wave64 max-reduce of the packed key into lane 63.
__device__ __forceinline__ unsigned long long wave_max_key(unsigned long long k) {
  k = u64max(k, dpp_u64<0x111, 0xF>(k));
  k = u64max(k, dpp_u64<0x112, 0xF>(k));
  k = u64max(k, dpp_u64<0x114, 0xF>(k));
  k = u64max(k, dpp_u64<0x118, 0xF>(k));
  k = u64max(k, dpp_u64<0x142, 0xA>(k));
  k = u64max(k, dpp_u64<0x143, 0xC>(k));
  return k;
}

// ---------------- kNN: K smallest squared distances, tie -> lower index.
template<int K, int NC, int THREADS>
__global__ __launch_bounds__(THREADS) void knn_kernel(
    const float* __restrict__ pos, const int* __restrict__ qidx, int NQ,
    int* __restrict__ out_idx)
{
  const int b = blockIdx.y;
  const int s = blockIdx.x * THREADS + threadIdx.x;
  const int i = qidx ? qidx[b * NQ + s] : s;
  const float* P = pos + (size_t)b * NC * 3;
  const float xi = P[i * 3 + 0], yi = P[i * 3 + 1], zi = P[i * 3 + 2];
  const float ni = sqnorm3(xi, yi, zi);
  float bd[K]; int bj[K];
#pragma unroll
  for (int t = 0; t < K; ++t) { bd[t] = __builtin_inff(); bj[t] = 0; }
  __shared__ float4 tile[1024];
  for (int base = 0; base < NC; base += 1024) {
    __syncthreads();
    for (int t = threadIdx.x; t < 1024; t += THREADS) {
      const float* q = P + (size_t)(base + t) * 3;
      const float x = q[0], y = q[1], z = q[2];
      tile[t] = make_float4(x, y, z, sqnorm3(x, y, z));
    }
    __syncthreads();
#pragma unroll 2
    for (int t = 0; t < 1024; ++t) {
      const float4 q = tile[t];
      const float dot = f_add(f_add(f_mul(xi, q.x), f_mul(yi, q.y)), f_mul(zi, q.z));
      const float d = f_sub(f_add(ni, q.w), f_mul(2.0f, dot));
      if (d < bd[K - 1]) {          // strict < keeps earlier index on ties
        bd[K - 1] = d; bj[K - 1] = base + t;
#pragma unroll
        for (int r = K - 1; r > 0; --r) {
          if (bd[r] < bd[r - 1]) {
            float td = bd[r]; bd[r] = bd[r - 1]; bd[r - 1] = td;
            int   tj = bj[r]; bj[r] = bj[r - 1]; bj[r - 1] = tj;
          } else break;
        }
      }
    }
  }
  int* o = out_idx + ((size_t)b * NQ + s) * K;
#pragma unroll
  for (int t = 0; t < K; ++t) o[t] = bj[t];
}

// ---------------- Farthest point sampling, exact replica of reference scan.
// 512 threads (8 waves): halves DPP + atomic overhead vs 1024 while E-loop
// issue is N-proportional (unchanged). float2 packed updates (v_pk_* fp32,
// contraction OFF so arithmetic is bit-identical to scalar rn ops).
template<int N, int M, int THREADS>
__global__ __launch_bounds__(THREADS) void fps_kernel(
    const float* __restrict__ pos, int* __restrict__ samp, float* __restrict__ pos_out)
{
#pragma clang fp contract(off)
  constexpr int E = N / THREADS;
  constexpr int P2 = E / 2;
  static_assert(E * THREADS == N && (E % 2) == 0, "");
  __shared__ float px[N], py[N], pz[N];
  __shared__ unsigned long long slot[3];
  const int b = blockIdx.x;
  const int tid = threadIdx.x;
  const float* P = pos + (size_t)b * N * 3;
  for (int t = tid; t < N; t += THREADS) {
    px[t] = P[t * 3 + 0]; py[t] = P[t * 3 + 1]; pz[t] = P[t * 3 + 2];
  }
  if (tid < 3) slot[tid] = 0ull;
  __syncthreads();
  const float x0 = px[0], y0 = py[0], z0 = pz[0];
  v2f X2[P2], Y2[P2], Z2[P2], MD2[P2];
  unsigned ILO[E];
  unsigned long long key = 0;
  {
    const v2f x0v = {x0, x0}, y0v = {y0, y0}, z0v = {z0, z0};
#pragma unroll
    for (int p = 0; p < P2; ++p) {
      const int g0 = (2 * p) * THREADS + tid, g1 = g0 + THREADS;
      X2[p] = (v2f){px[g0], px[g1]};
      Y2[p] = (v2f){py[g0], py[g1]};
      Z2[p] = (v2f){pz[g0], pz[g1]};
      const v2f dx = X2[p] - x0v, dy = Y2[p] - y0v, dz = Z2[p] - z0v;
      const v2f m0 = dx * dx, m1 = dy * dy, m2 = dz * dz;
      MD2[p] = (m0 + m1) + m2;
      ILO[2 * p]     = 0xFFFFFFFFu - (unsigned)g0;
      ILO[2 * p + 1] = 0xFFFFFFFFu - (unsigned)g1;
      const unsigned long long k0 =
          ((unsigned long long)__float_as_uint(MD2[p].x) << 32) | ILO[2 * p];
      const unsigned long long k1 =
          ((unsigned long long)__float_as_uint(MD2[p].y) << 32) | ILO[2 * p + 1];
      key = u64max(key, u64max(k0, k1));
    }
  }
  if (tid == 0) {
    samp[b * M] = 0;
    pos_out[(size_t)b * M * 3 + 0] = x0;
    pos_out[(size_t)b * M * 3 + 1] = y0;
    pos_out[(size_t)b * M * 3 + 2] = z0;
  }
  const int lane = tid & 63;
  int cur = 1;  // slot index = s % 3
#pragma unroll 1
  for (int s = 1; s < M; ++s) {
    const unsigned long long wk = wave_max_key(key);
    if (lane == 63) atomicMax(&slot[cur], wk);
    __syncthreads();
    const unsigned long long w = slot[cur];
    const int gi = (int)(0xFFFFFFFFu - (unsigned)w);
    const float sx = px[gi], sy = py[gi], sz = pz[gi];
    const int prev = cur == 0 ? 2 : cur - 1;
    if (tid == 0) {
      slot[prev] = 0ull;  // reset barrier-ordered: last read s-1, next write s+2
      samp[b * M + s] = gi;
      float* po = pos_out + ((size_t)b * M + s) * 3;
      po[0] = sx; po[1] = sy; po[2] = sz;
    }
    cur = cur == 2 ? 0 : cur + 1;
    key = 0;
    const v2f sxv = {sx, sx}, syv = {sy, sy}, szv = {sz, sz};
#pragma unroll
    for (int p = 0; p < P2; ++p) {
      const v2f dx = X2[p] - sxv, dy = Y2[p] - syv, dz = Z2[p] - szv;
      const v2f m0 = dx * dx, m1 = dy * dy, m2 = dz * dz;
      const v2f d = (m0 + m1) + m2;
      MD2[p] = __builtin_elementwise_min(MD2[p], d);
      const unsigned long long k0 =
          ((unsigned long long)__float_as_uint(MD2[p].x) << 32) | ILO[2 * p];
      const unsigned long long k1 =
          ((unsigned long long)__float_as_uint(MD2[p].y) << 32) | ILO[2 * p + 1];
      key = u64max(key, u64max(k0, k1));
    }
  }
}

__device__ __forceinline__ float f4c(const float4& v, int c) {
  return c == 0 ? v.x : c == 1 ? v.y : c == 2 ? v.z : v.w;
}
__device__ __forceinline__ void fma4(float4& a, float v, const float4& w) {
  a.x += v * w.x; a.y += v * w.y; a.z += v * w.z; a.w += v * w.w;
}

// ---------------- PointNet edge layer, weight-read-amortized:
//  - h_i contribution of layer 1 is edge-independent -> computed once (abase)
//  - edges processed in pairs sharing every LDS weight read (~2x fewer reads)
//  - layer 2 in two output halves to cap register pressure
template<int K, int NC, int C>
__global__ __launch_bounds__(64) void pn_layer_kernel(
    const float* __restrict__ h, const float* __restrict__ pos,
    const int* __restrict__ qidx, int NQ, const int* __restrict__ knn,
    const float* __restrict__ W1, const float* __restrict__ b1,
    const float* __restrict__ W2, const float* __restrict__ b2,
    float* __restrict__ hout)
{
  constexpr int CIN = 2 * C + 3;
  __shared__ float4 sW1[CIN * 8];
  __shared__ float4 sW2[32 * 8];
  __shared__ float sb1[32], sb2[32];
  for (int t = threadIdx.x; t < CIN * 8; t += 64) sW1[t] = ((const float4*)W1)[t];
  for (int t = threadIdx.x; t < 32 * 8; t += 64) sW2[t] = ((const float4*)W2)[t];
  if (threadIdx.x < 32) { sb1[threadIdx.x] = b1[threadIdx.x]; sb2[threadIdx.x] = b2[threadIdx.x]; }
  __syncthreads();
  const int b = blockIdx.y;
  const int s = blockIdx.x * 64 + threadIdx.x;
  const int i = qidx ? qidx[b * NQ + s] : s;
  const float* P = pos + (size_t)b * NC * 3;
  const float* H = h + (size_t)b * NC * C;
  const float xi = P[i * 3], yi = P[i * 3 + 1], zi = P[i * 3 + 2];
  float4 abase[8];
#pragma unroll
  for (int o = 0; o < 8; ++o)
    abase[o] = make_float4(sb1[4 * o], sb1[4 * o + 1], sb1[4 * o + 2], sb1[4 * o + 3]);
  if constexpr (C == 1) {
    const float v = H[i];
#pragma unroll
    for (int o = 0; o < 8; ++o) fma4(abase[o], v, sW1[o]);
  } else {
    const float4* Hi = (const float4*)(H + (size_t)i * C);
#pragma unroll
    for (int c4 = 0; c4 < C / 4; ++c4) {
      const float4 hv = Hi[c4];
#pragma unroll
      for (int q = 0; q < 4; ++q) {
        const float v = f4c(hv, q);
#pragma unroll
        for (int o = 0; o < 8; ++o) fma4(abase[o], v, sW1[(4 * c4 + q) * 8 + o]);
      }
    }
  }
  float4 best[8];
#pragma unroll
  for (int o = 0; o < 8; ++o)
    best[o] = make_float4(-__builtin_inff(), -__builtin_inff(), -__builtin_inff(), -__builtin_inff());
  const int* kn = knn + ((size_t)b * NQ + s) * K;

  auto edge_pair = [&](int j0, int j1) {
    float4 a0[8], a1[8];
#pragma unroll
    for (int o = 0; o < 8; ++o) { a0[o] = abase[o]; a1[o] = abase[o]; }
    const float rx0 = P[j0 * 3] - xi, ry0 = P[j0 * 3 + 1] - yi, rz0 = P[j0 * 3 + 2] - zi;
    const float rx1 = P[j1 * 3] - xi, ry1 = P[j1 * 3 + 1] - yi, rz1 = P[j1 * 3 + 2] - zi;
    if constexpr (C == 1) {
      const float v0 = H[j0], v1 = H[j1];
#pragma unroll
      for (int o = 0; o < 8; ++o) {
        const float4 w = sW1[C * 8 + o];
        fma4(a0[o], v0, w); fma4(a1[o], v1, w);
      }
    } else {
      const float4* Hj0 = (const float4*)(H + (size_t)j0 * C);
      const float4* Hj1 = (const float4*)(H + (size_t)j1 * C);
#pragma unroll
      for (int c4 = 0; c4 < C / 4; ++c4) {
        const float4 h0 = Hj0[c4], h1 = Hj1[c4];
#pragma unroll
        for (int q = 0; q < 4; ++q) {
          const float v0 = f4c(h0, q), v1 = f4c(h1, q);
#pragma unroll
          for (int o = 0; o < 8; ++o) {
            const float4 w = sW1[(C + 4 * c4 + q) * 8 + o];
            fma4(a0[o], v0, w); fma4(a1[o], v1, w);
          }
        }
      }
    }
    const float r0[3] = {rx0, ry0, rz0}, r1[3] = {rx1, ry1, rz1};
#pragma unroll
    for (int r = 0; r < 3; ++r) {
#pragma unroll
      for (int o = 0; o < 8; ++o) {
        const float4 w = sW1[(2 * C + r) * 8 + o];
        fma4(a0[o], r0[r], w); fma4(a1[o], r1[r], w);
      }
    }
#pragma unroll
    for (int o = 0; o < 8; ++o) {
      a0[o].x = fmaxf(a0[o].x, 0.f); a0[o].y = fmaxf(a0[o].y, 0.f);
      a0[o].z = fmaxf(a0[o].z, 0.f); a0[o].w = fmaxf(a0[o].w, 0.f);
      a1[o].x = fmaxf(a1[o].x, 0.f); a1[o].y = fmaxf(a1[o].y, 0.f);
      a1[o].z = fmaxf(a1[o].z, 0.f); a1[o].w = fmaxf(a1[o].w, 0.f);
    }
#pragma unroll
    for (int hf = 0; hf < 2; ++hf) {
      float4 m0[4], m1[4];
#pragma unroll
      for (int o4 = 0; o4 < 4; ++o4) {
        const int c0 = 16 * hf + 4 * o4;
        m0[o4] = make_float4(sb2[c0], sb2[c0 + 1], sb2[c0 + 2], sb2[c0 + 3]);
        m1[o4] = m0[o4];
      }
#pragma unroll
      for (int c = 0; c < 32; ++c) {
        const float v0 = f4c(a0[c >> 2], c & 3), v1 = f4c(a1[c >> 2], c & 3);
#pragma unroll
        for (int o4 = 0; o4 < 4; ++o4) {
          const float4 w = sW2[c * 8 + hf * 4 + o4];
          fma4(m0[o4], v0, w); fma4(m1[o4], v1, w);
        }
      }
#pragma unroll
      for (int o4 = 0; o4 < 4; ++o4) {
        float4& bb = best[hf * 4 + o4];
        bb.x = fmaxf(bb.x, fmaxf(m0[o4].x, m1[o4].x));
        bb.y = fmaxf(bb.y, fmaxf(m0[o4].y, m1[o4].y));
        bb.z = fmaxf(bb.z, fmaxf(m0[o4].z, m1[o4].z));
        bb.w = fmaxf(bb.w, fmaxf(m0[o4].w, m1[o4].w));
      }
    }
  };

  auto edge_single = [&](int j0) {
    float4 a0[8];
#pragma unroll
    for (int o = 0; o < 8; ++o) a0[o] = abase[o];
    const float rx0 = P[j0 * 3] - xi, ry0 = P[j0 * 3 + 1] - yi, rz0 = P[j0 * 3 + 2] - zi;
    if constexpr (C == 1) {
      const float v0 = H[j0];
#pragma unroll
      for (int o = 0; o < 8; ++o) fma4(a0[o], v0, sW1[C * 8 + o]);
    } else {
      const float4* Hj0 = (const float4*)(H + (size_t)j0 * C);
#pragma unroll
      for (int c4 = 0; c4 < C / 4; ++c4) {
        const float4 h0 = Hj0[c4];
#pragma unroll
        for (int q = 0; q < 4; ++q) {
          const float v0 = f4c(h0, q);
#pragma unroll
          for (int o = 0; o < 8; ++o) fma4(a0[o], v0, sW1[(C + 4 * c4 + q) * 8 + o]);
        }
      }
    }
    const float r0[3] = {rx0, ry0, rz0};
#pragma unroll
    for (int r = 0; r < 3; ++r)
#pragma unroll
      for (int o = 0; o < 8; ++o) fma4(a0[o], r0[r], sW1[(2 * C + r) * 8 + o]);
#pragma unroll
    for (int o = 0; o < 8; ++o) {
      a0[o].x = fmaxf(a0[o].x, 0.f); a0[o].y = fmaxf(a0[o].y, 0.f);
      a0[o].z = fmaxf(a0[o].z, 0.f); a0[o].w = fmaxf(a0[o].w, 0.f);
    }
#pragma unroll
    for (int hf = 0; hf < 2; ++hf) {
      float4 m0[4];
#pragma unroll
      for (int o4 = 0; o4 < 4; ++o4) {
        const int c0 = 16 * hf + 4 * o4;
        m0[o4] = make_float4(sb2[c0], sb2[c0 + 1], sb2[c0 + 2], sb2[c0 + 3]);
      }
#pragma unroll
      for (int c = 0; c < 32; ++c) {
        const float v0 = f4c(a0[c >> 2], c & 3);
#pragma unroll
        for (int o4 = 0; o4 < 4; ++o4) fma4(m0[o4], v0, sW2[c * 8 + hf * 4 + o4]);
      }
#pragma unroll
      for (int o4 = 0; o4 < 4; ++o4) {
        float4& bb = best[hf * 4 + o4];
        bb.x = fmaxf(bb.x, m0[o4].x); bb.y = fmaxf(bb.y, m0[o4].y);
        bb.z = fmaxf(bb.z, m0[o4].z); bb.w = fmaxf(bb.w, m0[o4].w);
      }
    }
  };

#pragma unroll
  for (int e = 0; e + 1 < K; e += 2) edge_pair(kn[e], kn[e + 1]);
  if constexpr (K & 1) edge_single(kn[K - 1]);

  float4* ho = (float4*)(hout + ((size_t)b * NQ + s) * 32);
#pragma unroll
  for (int o = 0; o < 8; ++o)
    ho[o] = make_float4(fmaxf(best[o].x, 0.0f), fmaxf(best[o].y, 0.0f),
                        fmaxf(best[o].z, 0.0f), fmaxf(best[o].w, 0.0f));
}

// ---------------- global max pool over N3 points + final linear 32->10
__global__ __launch_bounds__(256) void final_kernel(
    const float* __restrict__ h, const float* __restrict__ Wr,
    const float* __restrict__ br, float* __restrict__ out)
{
  __shared__ float red[8][32];
  __shared__ float g[32];
  const int b = blockIdx.x;
  const int c = threadIdx.x & 31, grp = threadIdx.x >> 5;
  const float* H = h + (size_t)b * NP3 * 32;
  float m = -__builtin_inff();
  for (int r = grp; r < NP3; r += 8) m = fmaxf(m, H[r * 32 + c]);
  red[grp][c] = m;
  __syncthreads();
  if (threadIdx.x < 32) {
    float v = red[0][c];
#pragma unroll
    for (int w = 1; w < 8; ++w) v = fmaxf(v, red[w][c]);
    g[c] = v;
  }
  __syncthreads();
  if (threadIdx.x < 10) {
    float v = br[threadIdx.x];
#pragma unroll
    for (int cc = 0; cc < 32; ++cc) v += g[cc] * Wr[cc * 10 + threadIdx.x];
    out[b * 10 + threadIdx.x] = v;
  }
}

extern "C" void kernel_launch(void* const* d_in, const int* in_sizes, int n_in,
                              void* d_out, int out_size, void* d_ws, size_t ws_size,
                              hipStream_t stream) {
  const float* x   = (const float*)d_in[0];
  const float* pos = (const float*)d_in[1];
  const float* W11 = (const float*)d_in[2];
  const float* b11 = (const float*)d_in[3];
  const float* W12 = (const float*)d_in[4];
  const float* b12 = (const float*)d_in[5];
  const float* W21 = (const float*)d_in[6];
  const float* b21 = (const float*)d_in[7];
  const float* W22 = (const float*)d_in[8];
  const float* b22 = (const float*)d_in[9];
  const float* W31 = (const float*)d_in[10];
  const float* b31 = (const float*)d_in[11];
  const float* W32 = (const float*)d_in[12];
  const float* b32 = (const float*)d_in[13];
  const float* Wr  = (const float*)d_in[14];
  const float* br  = (const float*)d_in[15];
  float* out = (float*)d_out;

  char* p = (char*)d_ws;
  auto alloc = [&](size_t bytes) {
    char* r = p; p += (bytes + 255) & ~(size_t)255; return r;
  };
  int*   samp1 = (int*)  alloc(sizeof(int)   * BATCH * NP2);
  float* pos2  = (float*)alloc(sizeof(float) * BATCH * NP2 * 3);
  int*   samp2 = (int*)  alloc(sizeof(int)   * BATCH * NP3);
  float* pos3  = (float*)alloc(sizeof(float) * BATCH * NP3 * 3);
  int*   idx1  = (int*)  alloc(sizeof(int)   * BATCH * NP2 * 6);
  float* h2in  = (float*)alloc(sizeof(float) * BATCH * NP2 * 32);
  int*   idx2  = (int*)  alloc(sizeof(int)   * BATCH * NP3 * 4);
  float* h3in  = (float*)alloc(sizeof(float) * BATCH * NP3 * 32);
  int*   idx3  = (int*)  alloc(sizeof(int)   * BATCH * NP3 * 3);
  float* h3    = (float*)alloc(sizeof(float) * BATCH * NP3 * 32);

  fps_kernel<NP1, NP2, 512><<<BATCH, 512, 0, stream>>>(pos, samp1, pos2);
  fps_kernel<NP2, NP3, 512><<<BATCH, 512, 0, stream>>>(pos2, samp2, pos3);

  knn_kernel<6, NP1, 128><<<dim3(NP2 / 128, BATCH), 128, 0, stream>>>(pos, samp1, NP2, idx1);
  pn_layer_kernel<6, NP1, 1><<<dim3(NP2 / 64, BATCH), 64, 0, stream>>>(
      x, pos, samp1, NP2, idx1, W11, b11, W12, b12, h2in);

  knn_kernel<4, NP2, 64><<<dim3(NP3 / 64, BATCH), 64, 0, stream>>>(pos2, samp2, NP3, idx2);
  pn_layer_kernel<4, NP2, 32><<<dim3(NP3 / 64, BATCH), 64, 0, stream>>>(
      h2in, pos2, samp2, NP3, idx2, W21, b21, W22, b22, h3in);

  knn_kernel<3, NP3, 64><<<dim3(NP3 / 64, BATCH), 64, 0, stream>>>(pos3, nullptr, NP3, idx3);
  pn_layer_kernel<3, NP3, 32><<<dim3(NP3 / 64, BATCH), 64, 0, stream>>>(
      h3in, pos3, nullptr, NP3, idx3, W31, b31, W32, b32, h3);

  final_kernel<<<BATCH, 256, 0, stream>>>(h3, Wr, br, out);
}